// Round 1
// 620.826 us; speedup vs baseline: 1.1949x; 1.1949x over previous
//
#include <hip/hip_runtime.h>
#include <cstdint>
#include <cstddef>

// ExllamaLinear: out[M,N] = f16( f16( x[M,K] @ ((q - z) * s)[K,N] ) + bias )
// M = 4096, K = 4096, N = 11008, group 128 along K. fp16 tensors stored f32.
//
// R6: 256x256 deep-pipelined GEMM (T3+T4+T5 port):
//   - BK=32, 4-deep LDS ring buffer (4 x 32KB = 128KB): stage tile t+3 while
//     computing tile t; boundary wait is counted s_waitcnt vmcnt(8) (never 0
//     in main loop), raw s_barrier (no vmcnt drain).
//   - 2 phases per K-tile: {ds_read frags || issue 2 global_load_lds} ->
//     barrier -> 16 MFMA in s_setprio(1) -> barrier.
//   - workspace re-tiled for BK=32: tile (t128,kt32) = 512 granules of 16B;
//     granule g: row r=g>>3? no: r=g>>2, slot s=g&3 holds k-granule
//     kq = s ^ ((r>>1)&3)  (spreads 16 consecutive rows across all 8
//     16B-bank-groups -> 2 lanes/group on ds_read_b128 = conflict-free).
//   - prepasses emit that layout; GEMM staging reads are sequential 16B.

typedef unsigned short u16;
typedef u16    u16x8  __attribute__((ext_vector_type(8)));
typedef __bf16 bfv8   __attribute__((ext_vector_type(8)));
typedef float  f32x4  __attribute__((ext_vector_type(4)));

#define K_DIM 4096
#define N_DIM 11008
#define GS    128
#define KT32  (K_DIM / 32)   // 128 k-tiles of 32
#define LSTR  72             // fused-fallback padded LDS stride

__device__ __forceinline__ u16 f2bf(float f) {  // RTNE f32 -> bf16 bits
  union { float f; uint32_t u; } v;
  v.f = f;
  uint32_t u = v.u + 0x7FFFu + ((v.u >> 16) & 1u);
  return (u16)(u >> 16);
}
__device__ __forceinline__ float f16r(float v) {  // fp16 round-trip (RTNE)
  return (float)(_Float16)v;
}
__device__ __forceinline__ void async_load16(const u16* g, u16* l) {
  __builtin_amdgcn_global_load_lds(
      (const __attribute__((address_space(1))) uint32_t*)g,
      (__attribute__((address_space(3))) uint32_t*)l, 16, 0, 0);
}

// ---------------------------------------------------------------------------
// Pre-pass A: x f32 -> bf16 bits, BK=32 tiles. Tile (mt,kt) = 128 rows x 32 k
// = 512 granules. granule g: r=g>>2, s=g&3, kq=s^((r>>1)&3). Writes are
// lane-sequential 16B.
// ---------------------------------------------------------------------------
__global__ __launch_bounds__(256) void convert_x32(
    const float* __restrict__ x, u16* __restrict__ xb) {
  const int kt = blockIdx.x, mt = blockIdx.y;
  const int m0 = mt * 128, k0 = kt * 32;
  u16* dst = xb + ((size_t)mt * KT32 + kt) * 4096;
#pragma unroll
  for (int i = 0; i < 2; ++i) {
    const int g = i * 256 + threadIdx.x;
    const int r = g >> 2, s = g & 3;
    const int kq = s ^ ((r >> 1) & 3);
    const float* sp = x + (size_t)(m0 + r) * K_DIM + (k0 + kq * 8);
    const f32x4 p = *(const f32x4*)sp;
    const f32x4 q = *(const f32x4*)(sp + 4);
    u16x8 o;
#pragma unroll
    for (int t = 0; t < 4; ++t) { o[t] = f2bf(p[t]); o[t + 4] = f2bf(q[t]); }
    *(u16x8*)(dst + (size_t)g * 8) = o;
  }
}

// ---------------------------------------------------------------------------
// Pre-pass B: dequant int4 -> Wt bf16 bits, BK=32 tiles (128 n-rows x 32 k).
// One granule = one qweight int32 (8 nibbles along K).
// ---------------------------------------------------------------------------
__global__ __launch_bounds__(256) void dequant32(
    const uint32_t* __restrict__ qweight, const uint32_t* __restrict__ qzeros,
    const float* __restrict__ scales, u16* __restrict__ wt) {
  const int kt = blockIdx.x, nt = blockIdx.y;
  const int n0 = nt * 128;
  const int gq = kt >> 2;                       // quant group = kt*32/128
  u16* dst = wt + ((size_t)nt * KT32 + kt) * 4096;
#pragma unroll
  for (int i = 0; i < 2; ++i) {
    const int g = i * 256 + threadIdx.x;
    const int r = g >> 2, s = g & 3;
    const int kq = s ^ ((r >> 1) & 3);
    const int n = n0 + r;
    const uint32_t zq = qzeros[(size_t)gq * (N_DIM / 8) + (n >> 3)];
    const int   z   = (int)((zq >> ((n & 7) * 4)) & 15u);
    const float sc  = scales[(size_t)gq * N_DIM + n];
    const float nzs = -sc * (float)z;           // w = fma(q,s,-z*s): exact in f32
    const uint32_t q = qweight[(size_t)(kt * 4 + kq) * N_DIM + n];
    u16x8 o;
#pragma unroll
    for (int t = 0; t < 8; ++t) {
      const int qv = (int)((q >> (t * 4)) & 15u);
      o[t] = f2bf(fmaf((float)qv, sc, nzs));
    }
    *(u16x8*)(dst + (size_t)g * 8) = o;
  }
}

// ---------------------------------------------------------------------------
// GEMM: 256x256 tile, BK=32, 8 waves (2M x 4N), per-wave 128x64 output
// (8x4 16x16x32 frags). 4-deep LDS ring, counted vmcnt, setprio MFMA.
// ---------------------------------------------------------------------------
#define STAGE_A(t) do {                                                      \
    const int sb_ = (t) & 3;                                                 \
    async_load16(atile + ((size_t)0 * KT32 + (t)) * 4096 + tid * 8,          \
                 As + sb_ * 8192 + 0 * 4096 + wave * 512);                   \
    async_load16(atile + ((size_t)1 * KT32 + (t)) * 4096 + tid * 8,          \
                 As + sb_ * 8192 + 1 * 4096 + wave * 512);                   \
  } while (0)
#define STAGE_B(t) do {                                                      \
    const int sb_ = (t) & 3;                                                 \
    async_load16(btile + ((size_t)0 * KT32 + (t)) * 4096 + tid * 8,          \
                 Bs + sb_ * 8192 + 0 * 4096 + wave * 512);                   \
    async_load16(btile + ((size_t)1 * KT32 + (t)) * 4096 + tid * 8,          \
                 Bs + sb_ * 8192 + 1 * 4096 + wave * 512);                   \
  } while (0)
#define LDF(base, off) __builtin_bit_cast(bfv8, *(const u16x8*)((base) + (off)))
#define MF(i, j, av, bv)                                                     \
  acc[i][j] = __builtin_amdgcn_mfma_f32_16x16x32_bf16((av), (bv), acc[i][j], 0, 0, 0)

__global__ __launch_bounds__(512, 2) void gemm_256(
    const u16* __restrict__ xb, const u16* __restrict__ wt,
    const float* __restrict__ bias, float* __restrict__ out) {
  __shared__ __align__(16) u16 As[4 * 8192];   // 4 bufs x (2 halves x 4096)
  __shared__ __align__(16) u16 Bs[4 * 8192];

  const int tid  = threadIdx.x;
  const int lane = tid & 63;
  const int wave = tid >> 6;
  const int wm   = wave >> 2;        // 0..1  (M)
  const int wn   = wave & 3;         // 0..3  (N)
  const int lrow = lane & 15;
  const int lk   = lane >> 4;        // k-quad 0..3
  const int swz  = (lrow >> 1) & 3;  // read-side XOR swizzle key

  const int n0 = blockIdx.x * 256;
  const int m0 = blockIdx.y * 256;

  const u16* atile = xb + (size_t)(2 * blockIdx.y) * KT32 * 4096;
  const u16* btile = wt + (size_t)(2 * blockIdx.x) * KT32 * 4096;

  // LDS elem offsets of this lane's fragment granules (16B aligned)
  const int aoff = wm * 4096 + (lrow * 4 + (lk ^ swz)) * 8;
  const int boff = (wn >> 1) * 4096 + (((wn & 1) * 64 + lrow) * 4 + (lk ^ swz)) * 8;

  f32x4 acc[8][4];
#pragma unroll
  for (int i = 0; i < 8; ++i)
#pragma unroll
    for (int j = 0; j < 4; ++j) acc[i][j] = f32x4{0.f, 0.f, 0.f, 0.f};

  // prologue: stage tiles 0,1,2 (12 loads/wave); oldest 4 (tile 0) must land
  STAGE_A(0); STAGE_B(0); STAGE_A(1); STAGE_B(1); STAGE_A(2); STAGE_B(2);
  asm volatile("s_waitcnt vmcnt(8)" ::: "memory");
  asm volatile("s_barrier" ::: "memory");

#pragma unroll 4
  for (int t = 0; t < KT32; ++t) {
    const u16* A = As + (t & 3) * 8192;
    const u16* B = Bs + (t & 3) * 8192;
    bfv8 a[4], b[4];
    // ---- phase 0: b[0..3] + a[0..3] reads, stage A(t+3), 16 MFMA ----
#pragma unroll
    for (int j = 0; j < 4; ++j) b[j] = LDF(B, boff + j * 512);
#pragma unroll
    for (int i = 0; i < 4; ++i) a[i] = LDF(A, aoff + i * 512);
    if (t + 3 < KT32) STAGE_A(t + 3);
    asm volatile("s_barrier" ::: "memory");
    __builtin_amdgcn_s_setprio(1);
#pragma unroll
    for (int i = 0; i < 4; ++i)
#pragma unroll
      for (int j = 0; j < 4; ++j) MF(i, j, a[i], b[j]);
    __builtin_amdgcn_s_setprio(0);
    asm volatile("s_barrier" ::: "memory");
    // ---- phase 1: a[4..7] reads, stage B(t+3), 16 MFMA ----
#pragma unroll
    for (int i = 0; i < 4; ++i) a[i] = LDF(A, aoff + (4 + i) * 512);
    if (t + 3 < KT32) STAGE_B(t + 3);
    asm volatile("s_barrier" ::: "memory");
    __builtin_amdgcn_s_setprio(1);
#pragma unroll
    for (int i = 0; i < 4; ++i)
#pragma unroll
      for (int j = 0; j < 4; ++j) MF(4 + i, j, a[i], b[j]);
    __builtin_amdgcn_s_setprio(0);
    // ---- boundary: counted vmcnt (tile t+1 must be resident) ----
    if (t == KT32 - 1) break;                    // no LDS use after last tile
    if (t < KT32 - 3) {
      asm volatile("s_waitcnt vmcnt(8)" ::: "memory");
    } else if (t == KT32 - 3) {
      asm volatile("s_waitcnt vmcnt(4)" ::: "memory");
    } else {
      asm volatile("s_waitcnt vmcnt(0)" ::: "memory");
    }
    asm volatile("s_barrier" ::: "memory");
  }

  // epilogue: ref rounding f16(f16(acc) + bias); store f32.
  // C/D layout (m89): col = lane&15, row = (lane>>4)*4 + reg
#pragma unroll
  for (int j = 0; j < 4; ++j) {
    const int n = n0 + wn * 64 + j * 16 + lrow;
    const float bvf = bias[n];
#pragma unroll
    for (int i = 0; i < 8; ++i) {
      const int mrow = m0 + wm * 128 + i * 16 + lk * 4;
#pragma unroll
      for (int r = 0; r < 4; ++r) {
        out[(size_t)(mrow + r) * N_DIM + n] = f16r(f16r(acc[i][j][r]) + bvf);
      }
    }
  }
}

// ---------------------------------------------------------------------------
// Fused fallback (no workspace): R4 structure, register staging, padded LDS.
// ---------------------------------------------------------------------------
__global__ __launch_bounds__(256) void gemm_fused(
    const float* __restrict__ xf, const uint32_t* __restrict__ qw,
    const uint32_t* __restrict__ qzeros, const float* __restrict__ scales,
    const float* __restrict__ bias, float* __restrict__ out) {
  __shared__ __align__(16) u16 As[128 * LSTR];
  __shared__ __align__(16) u16 Bs[128 * LSTR];

  const int tid  = threadIdx.x;
  const int lane = tid & 63;
  const int wave = tid >> 6;
  const int n0 = blockIdx.x * 128;
  const int m0 = blockIdx.y * 128;
  const int m_off = (wave >> 1) * 64;
  const int n_off = (wave & 1) * 64;
  const int lrow  = lane & 15;
  const int lk    = lane >> 4;
  const int sm = tid >> 3;
  const int sc = tid & 7;

  f32x4 acc[4][4];
#pragma unroll
  for (int i = 0; i < 4; ++i)
#pragma unroll
    for (int j = 0; j < 4; ++j) acc[i][j] = f32x4{0.f, 0.f, 0.f, 0.f};

  const int ncol = n0 + (tid & 127);
  float s_cur = 0.f, nzs_cur = 0.f;

  for (int kt = 0; kt < K_DIM / 64; ++kt) {
    const int k0 = kt * 64;
    u16x8 av[4];
#pragma unroll
    for (int i = 0; i < 4; ++i) {
      const int m = i * 32 + sm;
      const float* sp = xf + (size_t)(m0 + m) * K_DIM + (k0 + sc * 8);
      const f32x4 p = *(const f32x4*)sp;
      const f32x4 q4 = *(const f32x4*)(sp + 4);
#pragma unroll
      for (int t = 0; t < 4; ++t) { av[i][t] = f2bf(p[t]); av[i][t+4] = f2bf(q4[t]); }
    }
    u16x8 bv[4];
    if ((k0 & (GS - 1)) == 0) {
      const int g = k0 >> 7;
      const uint32_t zq = qzeros[(size_t)g * (N_DIM / 8) + (ncol >> 3)];
      const int z = (int)((zq >> ((ncol & 7) * 4)) & 15u);
      s_cur = scales[(size_t)g * N_DIM + ncol];
      nzs_cur = -s_cur * (float)z;
    }
#pragma unroll
    for (int i = 0; i < 4; ++i) {
      const int k8l = (tid >> 7) + i * 2;
      const uint32_t q = qw[(size_t)(k0 / 8 + k8l) * N_DIM + ncol];
#pragma unroll
      for (int t = 0; t < 8; ++t) {
        const int qv = (int)((q >> (t * 4)) & 15u);
        bv[i][t] = f2bf(fmaf((float)qv, s_cur, nzs_cur));
      }
    }
#pragma unroll
    for (int i = 0; i < 4; ++i)
      *(u16x8*)&As[(i * 32 + sm) * LSTR + sc * 8] = av[i];
    {
      const int nl = tid & 127;
#pragma unroll
      for (int i = 0; i < 4; ++i) {
        const int k8l = (tid >> 7) + i * 2;
        *(u16x8*)&Bs[nl * LSTR + k8l * 8] = bv[i];
      }
    }
    __syncthreads();
#pragma unroll
    for (int ks = 0; ks < 2; ++ks) {
      const int c = (ks * 4 + lk) * 8;
      bfv8 a[4], b[4];
#pragma unroll
      for (int i = 0; i < 4; ++i)
        a[i] = __builtin_bit_cast(bfv8,
                 *(const u16x8*)&As[(m_off + i * 16 + lrow) * LSTR + c]);
#pragma unroll
      for (int j = 0; j < 4; ++j)
        b[j] = __builtin_bit_cast(bfv8,
                 *(const u16x8*)&Bs[(n_off + j * 16 + lrow) * LSTR + c]);
#pragma unroll
      for (int i = 0; i < 4; ++i)
#pragma unroll
        for (int j = 0; j < 4; ++j)
          acc[i][j] = __builtin_amdgcn_mfma_f32_16x16x32_bf16(a[i], b[j],
                                                              acc[i][j], 0, 0, 0);
    }
    __syncthreads();
  }
#pragma unroll
  for (int j = 0; j < 4; ++j) {
    const int n = n0 + n_off + j * 16 + lrow;
    const float bvf = bias[n];
#pragma unroll
    for (int i = 0; i < 4; ++i) {
      const int mrow = m0 + m_off + i * 16 + lk * 4;
#pragma unroll
      for (int r = 0; r < 4; ++r)
        out[(size_t)(mrow + r) * N_DIM + n] = f16r(f16r(acc[i][j][r]) + bvf);
    }
  }
}

extern "C" void kernel_launch(void* const* d_in, const int* in_sizes, int n_in,
                              void* d_out, int out_size, void* d_ws, size_t ws_size,
                              hipStream_t stream) {
  // Identify inputs by element count (all five distinct).
  const float* x = nullptr;      const uint32_t* qweight = nullptr;
  const uint32_t* qzeros = nullptr;
  const float* scales = nullptr; const float* bias = nullptr;
  int M = 4096;
  for (int i = 0; i < n_in; ++i) {
    const long long s = in_sizes[i];
    if      (s == (long long)(K_DIM / 8) * N_DIM) qweight = (const uint32_t*)d_in[i];
    else if (s == (long long)(K_DIM / GS) * (N_DIM / 8)) qzeros = (const uint32_t*)d_in[i];
    else if (s == (long long)(K_DIM / GS) * N_DIM) scales = (const float*)d_in[i];
    else if (s == (long long)N_DIM) bias = (const float*)d_in[i];
    else { x = (const float*)d_in[i]; M = (int)(s / K_DIM); }
  }
  float* out = (float*)d_out;

  const size_t xb_bytes = (size_t)M * K_DIM * sizeof(u16);      // 33.5 MB
  const size_t wt_bytes = (size_t)N_DIM * K_DIM * sizeof(u16);  // 90.2 MB

  if (ws_size >= xb_bytes + wt_bytes && (M % 256) == 0) {
    u16* xbp = (u16*)d_ws;
    u16* wtp = (u16*)((char*)d_ws + xb_bytes);
    convert_x32<<<dim3(KT32, M / 128), 256, 0, stream>>>(x, xbp);
    dequant32<<<dim3(KT32, N_DIM / 128), 256, 0, stream>>>(
        qweight, qzeros, scales, wtp);
    gemm_256<<<dim3(N_DIM / 256, M / 256), 512, 0, stream>>>(
        xbp, wtp, bias, out);
  } else {
    gemm_fused<<<dim3(N_DIM / 128, (M + 127) / 128), 256, 0, stream>>>(
        x, qweight, qzeros, scales, bias, out);
  }
}

// Round 2
// 614.257 us; speedup vs baseline: 1.2077x; 1.0107x over previous
//
#include <hip/hip_runtime.h>
#include <cstdint>
#include <cstddef>

// ExllamaLinear: out[M,N] = f16( f16( x[M,K] @ ((q - z) * s)[K,N] ) + bias )
// M = 4096, K = 4096, N = 11008, group 128 along K. fp16 tensors stored f32.
//
// R7: 256x256 GEMM, BK=64, 2-buffer LDS (128KB), 4 phases/K-tile with
// ONE-PHASE-LOOKAHEAD register pipelining:
//   window p = { ds_read frags for phase p+1 ; stage 1 half-tile ;
//                MFMA(p) on regs read in window p-1 ; s_barrier }
// so LDS reads execute UNDER the MFMA cluster (compiler emits counted
// lgkmcnt for the older reads only). Single barrier per phase. Staging:
// A(kt+1) halves at P0/P1, B(kt+2) halves at P2/P3 (B region dead after its
// tile's P0). One counted s_waitcnt vmcnt(2) per K-tile at P2-end (before
// the barrier -> cross-wave visibility); drain only in the 2-tile tail.
// Workspace: R5 BK=64 tiled+swizzled layout (granule g: row nl=g>>3,
// k-granule cg=(g&7)^(nl&7)); ds_read_b128 frag reads land 2 lanes/bank.

typedef unsigned short u16;
typedef u16    u16x8  __attribute__((ext_vector_type(8)));
typedef __bf16 bfv8   __attribute__((ext_vector_type(8)));
typedef float  f32x4  __attribute__((ext_vector_type(4)));

#define K_DIM 4096
#define N_DIM 11008
#define GS    128
#define KT64  (K_DIM / 64)   // 64 k-tiles of 64
#define LSTR  72             // fused-fallback padded LDS stride

__device__ __forceinline__ u16 f2bf(float f) {  // RTNE f32 -> bf16 bits
  union { float f; uint32_t u; } v;
  v.f = f;
  uint32_t u = v.u + 0x7FFFu + ((v.u >> 16) & 1u);
  return (u16)(u >> 16);
}
__device__ __forceinline__ float f16r(float v) {  // fp16 round-trip (RTNE)
  return (float)(_Float16)v;
}
__device__ __forceinline__ void async_load16(const u16* g, u16* l) {
  __builtin_amdgcn_global_load_lds(
      (const __attribute__((address_space(1))) uint32_t*)g,
      (__attribute__((address_space(3))) uint32_t*)l, 16, 0, 0);
}

// ---------------------------------------------------------------------------
// Pre-pass A: x f32 -> bf16 bits, [128][64] tiles, R5 swizzle. One block per
// (kt, mt); writes perfectly sequential 16B granules.
// ---------------------------------------------------------------------------
__global__ __launch_bounds__(256) void convert_x_tiled(
    const float* __restrict__ x, u16* __restrict__ xb) {
  const int kt = blockIdx.x, mt = blockIdx.y;
  const int k0 = kt * 64, m0 = mt * 128;
  u16* dst = xb + ((size_t)(mt * KT64 + kt)) * 8192;
#pragma unroll
  for (int i = 0; i < 4; ++i) {
    const int g  = i * 256 + threadIdx.x;
    const int nl = g >> 3;
    const int cg = (g & 7) ^ (nl & 7);
    const float* sp = x + (size_t)(m0 + nl) * K_DIM + (k0 + cg * 8);
    const f32x4 p = *(const f32x4*)sp;
    const f32x4 q = *(const f32x4*)(sp + 4);
    u16x8 o;
#pragma unroll
    for (int t = 0; t < 4; ++t) { o[t] = f2bf(p[t]); o[t + 4] = f2bf(q[t]); }
    *(u16x8*)(dst + (size_t)g * 8) = o;
  }
}

// ---------------------------------------------------------------------------
// Pre-pass B: dequantize int4 -> Wt bf16 bits, [128][64] tiles, R5 swizzle.
// One granule = one qweight int32 (8 nibbles along K).
// ---------------------------------------------------------------------------
__global__ __launch_bounds__(256) void dequant_tiled(
    const uint32_t* __restrict__ qweight, const uint32_t* __restrict__ qzeros,
    const float* __restrict__ scales, u16* __restrict__ wt) {
  const int kt = blockIdx.x, nt = blockIdx.y;
  const int n0 = nt * 128;
  const int gq = kt >> 1;                       // quant group = kt*64/128
  u16* dst = wt + ((size_t)(nt * KT64 + kt)) * 8192;
#pragma unroll
  for (int i = 0; i < 4; ++i) {
    const int g  = i * 256 + threadIdx.x;
    const int nl = g >> 3;
    const int cg = (g & 7) ^ (nl & 7);
    const int n  = n0 + nl;
    const uint32_t zq = qzeros[(size_t)gq * (N_DIM / 8) + (n >> 3)];
    const int   z   = (int)((zq >> ((n & 7) * 4)) & 15u);
    const float s   = scales[(size_t)gq * N_DIM + n];
    const float nzs = -s * (float)z;            // w = fma(q,s,-z*s): exact in f32
    const uint32_t q = qweight[(size_t)(kt * 8 + cg) * N_DIM + n];
    u16x8 o;
#pragma unroll
    for (int t = 0; t < 8; ++t) {
      const int qv = (int)((q >> (t * 4)) & 15u);
      o[t] = f2bf(fmaf((float)qv, s, nzs));
    }
    *(u16x8*)(dst + (size_t)g * 8) = o;
  }
}

// ---------------------------------------------------------------------------
// GEMM: 256x256 tile, BK=64, 8 waves (2M x 4N), per-wave 128x64 (8x4 frags).
// ---------------------------------------------------------------------------
#define LDF(p) __builtin_bit_cast(bfv8, *(const u16x8*)(p))
#define BAR()  asm volatile("s_barrier" ::: "memory")
#define VMW(n) asm volatile("s_waitcnt vmcnt(" #n ")" ::: "memory")

// stage half-tile h (row-tile 2*bxy+h) of K-tile ktt into buffer (ktt&1)
#define STAGE_AH(ktt, h) do {                                                 \
    const u16* s_ = at0 + ((size_t)(h) * KT64 + (ktt)) * 8192;                \
    u16* d_ = &As[(((ktt) & 1) * 16384) + (h) * 8192 + wave * 512];           \
    async_load16(s_ + (size_t)tid * 8, d_);                                   \
    async_load16(s_ + (size_t)(512 + tid) * 8, d_ + 4096);                    \
  } while (0)
#define STAGE_BH(ktt, h) do {                                                 \
    const u16* s_ = bt0 + ((size_t)(h) * KT64 + (ktt)) * 8192;                \
    u16* d_ = &Bs[(((ktt) & 1) * 16384) + (h) * 8192 + wave * 512];           \
    async_load16(s_ + (size_t)tid * 8, d_);                                   \
    async_load16(s_ + (size_t)(512 + tid) * 8, d_ + 4096);                    \
  } while (0)

// read A fragment pair {ib, ib+1} x {ks0, ks1} from buffer sbx
#define RD_AP(v, ib, sbx) do {                                                \
    v[0] = LDF(&As[(sbx) * 16384 + aoff + (ib) * 1024 + kq0]);                \
    v[1] = LDF(&As[(sbx) * 16384 + aoff + (ib) * 1024 + kq1]);                \
    v[2] = LDF(&As[(sbx) * 16384 + aoff + ((ib) + 1) * 1024 + kq0]);          \
    v[3] = LDF(&As[(sbx) * 16384 + aoff + ((ib) + 1) * 1024 + kq1]);          \
  } while (0)
// read all 8 B fragments (j 0..3 x ks 0..1) from buffer sbx
#define RD_B8(v, sbx) do {                                                    \
    _Pragma("unroll")                                                         \
    for (int j_ = 0; j_ < 4; ++j_) {                                          \
      v[2 * j_]     = LDF(&Bs[(sbx) * 16384 + boff + j_ * 1024 + kq0]);       \
      v[2 * j_ + 1] = LDF(&Bs[(sbx) * 16384 + boff + j_ * 1024 + kq1]);       \
    }                                                                         \
  } while (0)

// 16 MFMA for i-pair {ib, ib+1}: all j, both ks (dependent pairs 8 apart)
#define MM(ib, av, bv) do {                                                   \
    __builtin_amdgcn_s_setprio(1);                                            \
    _Pragma("unroll")                                                         \
    for (int ks_ = 0; ks_ < 2; ++ks_)                                         \
      _Pragma("unroll")                                                       \
      for (int ii_ = 0; ii_ < 2; ++ii_)                                       \
        _Pragma("unroll")                                                     \
        for (int j_ = 0; j_ < 4; ++j_)                                        \
          acc[(ib) + ii_][j_] = __builtin_amdgcn_mfma_f32_16x16x32_bf16(      \
              av[2 * ii_ + ks_], bv[2 * j_ + ks_], acc[(ib) + ii_][j_],       \
              0, 0, 0);                                                       \
    __builtin_amdgcn_s_setprio(0);                                            \
  } while (0)

// one K-tile: 4 windows, each {reads(p+1) ; stage ; MFMA(p) ; barrier}
#define KTILE_BODY(kt, sb, bcur, bnxt) do {                                   \
    RD_AP(a23, 2, sb);  STAGE_AH((kt) + 1, 0);  MM(0, a01, bcur);  BAR();     \
    RD_AP(a45, 4, sb);  STAGE_AH((kt) + 1, 1);  MM(2, a23, bcur);  BAR();     \
    RD_AP(a67, 6, sb);  STAGE_BH((kt) + 2, 0);  MM(4, a45, bcur);             \
    VMW(2);  BAR();                                                           \
    RD_B8(bnxt, (sb) ^ 1);  RD_AP(a01, 0, (sb) ^ 1);  STAGE_BH((kt) + 2, 1);  \
    MM(6, a67, bcur);  BAR();                                                 \
  } while (0)

__global__ __launch_bounds__(512, 2) void gemm_256(
    const u16* __restrict__ xb, const u16* __restrict__ wt,
    const float* __restrict__ bias, float* __restrict__ out) {
  __shared__ __align__(16) u16 As[2 * 16384];   // 2 bufs x 2 halves x 8192
  __shared__ __align__(16) u16 Bs[2 * 16384];

  const int tid  = threadIdx.x;
  const int lane = tid & 63;
  const int wave = tid >> 6;
  const int wm   = wave >> 2;        // 0..1  (M)
  const int wn   = wave & 3;         // 0..3  (N)
  const int lrow = lane & 15;
  const int lk   = lane >> 4;        // k-quad 0..3
  const int swz  = lrow & 7;

  // XCD-aware bijective block swizzle (valid when nwg % 8 == 0)
  const int nwg = gridDim.x * gridDim.y;
  int wg = blockIdx.y * gridDim.x + blockIdx.x;
  if ((nwg & 7) == 0) wg = (wg & 7) * (nwg >> 3) + (wg >> 3);
  const int bx = wg % gridDim.x;
  const int by = wg / gridDim.x;
  const int n0 = bx * 256;
  const int m0 = by * 256;

  const u16* at0 = xb + (size_t)(2 * by) * KT64 * 8192;
  const u16* bt0 = wt + (size_t)(2 * bx) * KT64 * 8192;

  const int aoff = wm * 8192 + lrow * 64;
  const int boff = (wn >> 1) * 8192 + ((wn & 1) * 64 + lrow) * 64;
  const int kq0  = (lk ^ swz) * 8;
  const int kq1  = ((4 + lk) ^ swz) * 8;

  bfv8 a01[4], a23[4], a45[4], a67[4], bA[8], bB[8];
  f32x4 acc[8][4];
#pragma unroll
  for (int i = 0; i < 8; ++i)
#pragma unroll
    for (int j = 0; j < 4; ++j) acc[i][j] = f32x4{0.f, 0.f, 0.f, 0.f};

  // prologue: A(0), B(0), B(1) staged; wait A(0),B(0) (B(1) stays in flight)
  STAGE_AH(0, 0); STAGE_AH(0, 1); STAGE_BH(0, 0); STAGE_BH(0, 1);
  STAGE_BH(1, 0); STAGE_BH(1, 1);
  VMW(4); BAR();
  RD_B8(bA, 0); RD_AP(a01, 0, 0);     // window "P3 of kt=-1"

#pragma unroll 1
  for (int kt2 = 0; kt2 < 31; ++kt2) {   // kt = 0..61
    const int kt = 2 * kt2;
    KTILE_BODY(kt,     0, bA, bB);
    KTILE_BODY(kt + 1, 1, bB, bA);
  }
  // kt = 62 (sb=0): no B(64) staging; drain A(63) at P2-end
  RD_AP(a23, 2, 0);  STAGE_AH(63, 0);  MM(0, a01, bA);  BAR();
  RD_AP(a45, 4, 0);  STAGE_AH(63, 1);  MM(2, a23, bA);  BAR();
  RD_AP(a67, 6, 0);                    MM(4, a45, bA);  VMW(0); BAR();
  RD_B8(bB, 1); RD_AP(a01, 0, 1);      MM(6, a67, bA);  BAR();
  // kt = 63 (sb=1): pure compute
  RD_AP(a23, 2, 1);  MM(0, a01, bB);  BAR();
  RD_AP(a45, 4, 1);  MM(2, a23, bB);  BAR();
  RD_AP(a67, 6, 1);  MM(4, a45, bB);  BAR();
                     MM(6, a67, bB);

  // epilogue: ref rounding f16(f16(acc) + bias); store f32.
  // C/D layout (m89): col = lane&15, row = (lane>>4)*4 + reg
#pragma unroll
  for (int j = 0; j < 4; ++j) {
    const int n = n0 + wn * 64 + j * 16 + lrow;
    const float bvf = bias[n];
#pragma unroll
    for (int i = 0; i < 8; ++i) {
      const int mrow = m0 + wm * 128 + i * 16 + lk * 4;
#pragma unroll
      for (int r = 0; r < 4; ++r) {
        out[(size_t)(mrow + r) * N_DIM + n] = f16r(f16r(acc[i][j][r]) + bvf);
      }
    }
  }
}

// ---------------------------------------------------------------------------
// Fused fallback (no workspace / odd M): R4 structure, register staging.
// ---------------------------------------------------------------------------
__global__ __launch_bounds__(256) void gemm_fused(
    const float* __restrict__ xf, const uint32_t* __restrict__ qw,
    const uint32_t* __restrict__ qzeros, const float* __restrict__ scales,
    const float* __restrict__ bias, float* __restrict__ out) {
  __shared__ __align__(16) u16 As[128 * LSTR];
  __shared__ __align__(16) u16 Bs[128 * LSTR];

  const int tid  = threadIdx.x;
  const int lane = tid & 63;
  const int wave = tid >> 6;
  const int n0 = blockIdx.x * 128;
  const int m0 = blockIdx.y * 128;
  const int m_off = (wave >> 1) * 64;
  const int n_off = (wave & 1) * 64;
  const int lrow  = lane & 15;
  const int lk    = lane >> 4;
  const int sm = tid >> 3;
  const int sc = tid & 7;

  f32x4 acc[4][4];
#pragma unroll
  for (int i = 0; i < 4; ++i)
#pragma unroll
    for (int j = 0; j < 4; ++j) acc[i][j] = f32x4{0.f, 0.f, 0.f, 0.f};

  const int ncol = n0 + (tid & 127);
  float s_cur = 0.f, nzs_cur = 0.f;

  for (int kt = 0; kt < K_DIM / 64; ++kt) {
    const int k0 = kt * 64;
    u16x8 av[4];
#pragma unroll
    for (int i = 0; i < 4; ++i) {
      const int m = i * 32 + sm;
      const float* sp = xf + (size_t)(m0 + m) * K_DIM + (k0 + sc * 8);
      const f32x4 p = *(const f32x4*)sp;
      const f32x4 q4 = *(const f32x4*)(sp + 4);
#pragma unroll
      for (int t = 0; t < 4; ++t) { av[i][t] = f2bf(p[t]); av[i][t+4] = f2bf(q4[t]); }
    }
    u16x8 bv[4];
    if ((k0 & (GS - 1)) == 0) {
      const int g = k0 >> 7;
      const uint32_t zq = qzeros[(size_t)g * (N_DIM / 8) + (ncol >> 3)];
      const int z = (int)((zq >> ((ncol & 7) * 4)) & 15u);
      s_cur = scales[(size_t)g * N_DIM + ncol];
      nzs_cur = -s_cur * (float)z;
    }
#pragma unroll
    for (int i = 0; i < 4; ++i) {
      const int k8l = (tid >> 7) + i * 2;
      const uint32_t q = qw[(size_t)(k0 / 8 + k8l) * N_DIM + ncol];
#pragma unroll
      for (int t = 0; t < 8; ++t) {
        const int qv = (int)((q >> (t * 4)) & 15u);
        bv[i][t] = f2bf(fmaf((float)qv, s_cur, nzs_cur));
      }
    }
#pragma unroll
    for (int i = 0; i < 4; ++i)
      *(u16x8*)&As[(i * 32 + sm) * LSTR + sc * 8] = av[i];
    {
      const int nl = tid & 127;
#pragma unroll
      for (int i = 0; i < 4; ++i) {
        const int k8l = (tid >> 7) + i * 2;
        *(u16x8*)&Bs[nl * LSTR + k8l * 8] = bv[i];
      }
    }
    __syncthreads();
#pragma unroll
    for (int ks = 0; ks < 2; ++ks) {
      const int c = (ks * 4 + lk) * 8;
      bfv8 a[4], b[4];
#pragma unroll
      for (int i = 0; i < 4; ++i)
        a[i] = __builtin_bit_cast(bfv8,
                 *(const u16x8*)&As[(m_off + i * 16 + lrow) * LSTR + c]);
#pragma unroll
      for (int j = 0; j < 4; ++j)
        b[j] = __builtin_bit_cast(bfv8,
                 *(const u16x8*)&Bs[(n_off + j * 16 + lrow) * LSTR + c]);
#pragma unroll
      for (int i = 0; i < 4; ++i)
#pragma unroll
        for (int j = 0; j < 4; ++j)
          acc[i][j] = __builtin_amdgcn_mfma_f32_16x16x32_bf16(a[i], b[j],
                                                              acc[i][j], 0, 0, 0);
    }
    __syncthreads();
  }
#pragma unroll
  for (int j = 0; j < 4; ++j) {
    const int n = n0 + n_off + j * 16 + lrow;
    const float bvf = bias[n];
#pragma unroll
    for (int i = 0; i < 4; ++i) {
      const int mrow = m0 + m_off + i * 16 + lk * 4;
#pragma unroll
      for (int r = 0; r < 4; ++r)
        out[(size_t)(mrow + r) * N_DIM + n] = f16r(f16r(acc[i][j][r]) + bvf);
    }
  }
}

extern "C" void kernel_launch(void* const* d_in, const int* in_sizes, int n_in,
                              void* d_out, int out_size, void* d_ws, size_t ws_size,
                              hipStream_t stream) {
  // Identify inputs by element count (all five distinct).
  const float* x = nullptr;      const uint32_t* qweight = nullptr;
  const uint32_t* qzeros = nullptr;
  const float* scales = nullptr; const float* bias = nullptr;
  int M = 4096;
  for (int i = 0; i < n_in; ++i) {
    const long long s = in_sizes[i];
    if      (s == (long long)(K_DIM / 8) * N_DIM) qweight = (const uint32_t*)d_in[i];
    else if (s == (long long)(K_DIM / GS) * (N_DIM / 8)) qzeros = (const uint32_t*)d_in[i];
    else if (s == (long long)(K_DIM / GS) * N_DIM) scales = (const float*)d_in[i];
    else if (s == (long long)N_DIM) bias = (const float*)d_in[i];
    else { x = (const float*)d_in[i]; M = (int)(s / K_DIM); }
  }
  float* out = (float*)d_out;

  const size_t xb_bytes = (size_t)M * K_DIM * sizeof(u16);      // 33.5 MB
  const size_t wt_bytes = (size_t)N_DIM * K_DIM * sizeof(u16);  // 90.2 MB

  if (ws_size >= xb_bytes + wt_bytes && (M % 256) == 0) {
    u16* xbp = (u16*)d_ws;
    u16* wtp = (u16*)((char*)d_ws + xb_bytes);
    convert_x_tiled<<<dim3(KT64, M / 128), 256, 0, stream>>>(x, xbp);
    dequant_tiled<<<dim3(KT64, N_DIM / 128), 256, 0, stream>>>(
        qweight, qzeros, scales, wtp);
    gemm_256<<<dim3(N_DIM / 256, M / 256), 512, 0, stream>>>(
        xbp, wtp, bias, out);
  } else {
    gemm_fused<<<dim3(N_DIM / 128, (M + 127) / 128), 256, 0, stream>>>(
        x, qweight, qzeros, scales, bias, out);
  }
}